// Round 4
// baseline (1890.036 us; speedup 1.0000x reference)
//
#include <hip/hip_runtime.h>
#include <hip/hip_bf16.h>
#include <stdint.h>

typedef __hip_bfloat16 bf16;
typedef __attribute__((ext_vector_type(8))) short short8;
typedef __attribute__((ext_vector_type(4))) float f32x4;
typedef __attribute__((ext_vector_type(4))) int int4v;

#define NN 200000    // nodes
#define NNPAD 200064 // 1563*128
#define NE 400000    // directed edges
#define DV 133
#define DE 14
#define DH 200
#define MT 128       // M rows per block
#define NT 13        // 13 col tiles of 16 (200 -> 208 padded)
#define NCH 782      // ceil(NN/256) scan chunks

#define CI 5         // K chunks Wi (147 -> 160)
#define CH 7         // K chunks Wh (200 -> 224)
#define CO 11        // K chunks Wo (333 -> 352)
#define KO 352
#define LDV 160      // Vb16 row stride (shorts)
#define LDS_ 224     // S row stride (shorts), cols 200..223 zero

#define MFMA(a, b, c) __builtin_amdgcn_mfma_f32_16x16x32_bf16((a), (b), (c), 0, 0, 0)

__device__ __forceinline__ float us2f(unsigned short u) {
  return __uint_as_float(((unsigned)u) << 16);
}
__device__ __forceinline__ unsigned short f2us(float f) {
  bf16 h = __float2bfloat16(f);
  return *reinterpret_cast<unsigned short*>(&h);
}
__device__ __forceinline__ short8 neg8(short8 x) {  // flip bf16 sign bits
  int4v v = *(int4v*)&x;
  v ^= (int)0x80008000;
  return *(short8*)&v;
}

// ---- W pack into MFMA-fragment order --------------------------------------
// frag f = ((c*13 + t)*64 + lane); lane = q*16+ln; elem j -> k = c*32+q*8+j,
// col = t*16+ln.  mode 0: W[k][col]; mode 1 (Wo permuted for A'=[Mv||V]):
// W[(k<200)?133+k:k-200][col], valid k<333.
__global__ __launch_bounds__(256) void prepwpack_kernel(
    const float* __restrict__ W, int Ksrc, int nchunks, int mode,
    unsigned short* __restrict__ out)
{
  int f = blockIdx.x * 256 + threadIdx.x;
  int total = nchunks * 13 * 64;
  if (f >= total) return;
  int c = f / 832, rem = f - c * 832;
  int t = rem >> 6, l = rem & 63;
  int q = l >> 4, ln = l & 15;
  int col = t * 16 + ln;
  short8 w;
#pragma unroll
  for (int j = 0; j < 8; ++j) {
    int k = c * 32 + q * 8 + j;
    float v = 0.f;
    if (col < DH) {
      if (mode == 0) {
        if (k < Ksrc) v = W[(size_t)k * DH + col];
      } else {
        if (k < 333) {
          int sr = (k < 200) ? (133 + k) : (k - 200);
          v = W[(size_t)sr * DH + col];
        }
      }
    }
    w[j] = (short)f2us(v);
  }
  *(short8*)&out[(size_t)f * 8] = w;
}

// -------- V -> bf16, padded row stride LDV (cols >= DV zero) -----------------
__global__ __launch_bounds__(256) void packv_kernel(
    const float* __restrict__ V, unsigned short* __restrict__ Vb)
{
  int idx = blockIdx.x * 256 + threadIdx.x;   // one short8 per thread
  if (idx >= NN * (LDV / 8)) return;
  int n = idx / (LDV / 8), g = idx - n * (LDV / 8);
  int k0 = g * 8;
  short8 w;
#pragma unroll
  for (int j = 0; j < 8; ++j) {
    int k = k0 + j;
    float v = (k < DV) ? V[(size_t)n * DV + k] : 0.f;
    w[j] = (short)f2us(v);
  }
  *(short8*)&Vb[(size_t)n * LDV + k0] = w;
}

// ---- per-edge tail for h0 chunk 4: Et[e][0..31] = k 128..159 of [V[src]||Ef]
__global__ __launch_bounds__(256) void packet_kernel(
    const float* __restrict__ V, const float* __restrict__ Ef,
    const int* __restrict__ src, unsigned short* __restrict__ Et)
{
  int idx = blockIdx.x * 256 + threadIdx.x;
  if (idx >= NE * 4) return;
  int e = idx >> 2, part = idx & 3;
  short8 w;
#pragma unroll
  for (int j = 0; j < 8; ++j) w[j] = 0;
  if (part == 0) {
    int s = src[e];
#pragma unroll
    for (int j = 0; j < 5; ++j) w[j] = (short)f2us(V[(size_t)s * DV + 128 + j]);
#pragma unroll
    for (int j = 5; j < 8; ++j) w[j] = (short)f2us(Ef[(size_t)e * DE + (j - 5)]);
  } else if (part == 1) {
#pragma unroll
    for (int j = 0; j < 8; ++j) w[j] = (short)f2us(Ef[(size_t)e * DE + 3 + j]);
  } else if (part == 2) {
#pragma unroll
    for (int j = 0; j < 3; ++j) w[j] = (short)f2us(Ef[(size_t)e * DE + 11 + j]);
  }
  *(short8*)&Et[(size_t)e * 32 + part * 8] = w;
}

// ---- fill Abuf cols 200..351 with bf16(V), zero pad; zero rows >= NN --------
__global__ __launch_bounds__(256) void packav_kernel(
    const float* __restrict__ V, unsigned short* __restrict__ Abuf)
{
  int idx = blockIdx.x * 256 + threadIdx.x;   // one short8 per thread
  if (idx >= NNPAD * (KO / 8)) return;
  int n = idx / (KO / 8), g = idx - n * (KO / 8);
  int k0 = g * 8;
  if (n < NN && k0 < 200) return;             // gather owns these
  short8 w;
#pragma unroll
  for (int j = 0; j < 8; ++j) {
    int k = k0 + j;
    float v = (n < NN && k >= 200 && k < 333) ? V[(size_t)n * DV + (k - 200)] : 0.f;
    w[j] = (short)f2us(v);
  }
  *(short8*)&Abuf[(size_t)n * KO + k0] = w;
}

// ---------------- CSR build: hist -> scan -> scatter --------------------------
__global__ __launch_bounds__(256) void hist_kernel(
    const int* __restrict__ dst, int* __restrict__ counts)
{
  int e = blockIdx.x * 256 + threadIdx.x;
  if (e < NE) atomicAdd(&counts[dst[e]], 1);
}

__global__ __launch_bounds__(256) void chunksum_kernel(
    const int* __restrict__ counts, int* __restrict__ chunkSum)
{
  int b = blockIdx.x, tid = threadIdx.x;
  int i = b * 256 + tid;
  int v = (i < NN) ? counts[i] : 0;
#pragma unroll
  for (int d = 32; d; d >>= 1) v += __shfl_down(v, d, 64);
  __shared__ int ws[4];
  if ((tid & 63) == 0) ws[tid >> 6] = v;
  __syncthreads();
  if (tid == 0) chunkSum[b] = ws[0] + ws[1] + ws[2] + ws[3];
}

__global__ __launch_bounds__(1024) void scanchunks_kernel(
    const int* __restrict__ chunkSum, int* __restrict__ chunkOff)
{
  __shared__ int s[1024];
  int tid = threadIdx.x;
  int v = (tid < NCH) ? chunkSum[tid] : 0;
  s[tid] = v;
  __syncthreads();
  for (int d = 1; d < 1024; d <<= 1) {
    int t = (tid >= d) ? s[tid - d] : 0;
    __syncthreads();
    s[tid] += t;
    __syncthreads();
  }
  if (tid < NCH) chunkOff[tid] = s[tid] - v;  // exclusive
}

__global__ __launch_bounds__(256) void scanlocal_kernel(
    const int* __restrict__ counts, const int* __restrict__ chunkOff,
    int* __restrict__ offsets, int* __restrict__ cursor)
{
  __shared__ int s[256];
  int b = blockIdx.x, tid = threadIdx.x;
  int i = b * 256 + tid;
  int v = (i < NN) ? counts[i] : 0;
  s[tid] = v;
  __syncthreads();
  for (int d = 1; d < 256; d <<= 1) {
    int t = (tid >= d) ? s[tid - d] : 0;
    __syncthreads();
    s[tid] += t;
    __syncthreads();
  }
  if (i < NN) {
    int off = chunkOff[b] + s[tid] - v;
    offsets[i] = off;
    cursor[i] = off;
  }
  if (i == 0) offsets[NN] = NE;
}

__global__ __launch_bounds__(256) void scatter_kernel(
    const int* __restrict__ dst, int* __restrict__ cursor, int* __restrict__ perm)
{
  int e = blockIdx.x * 256 + threadIdx.x;
  if (e < NE) {
    int p = atomicAdd(&cursor[dst[e]], 1);
    perm[p] = e;
  }
}

// ---------------- H0 = relu([V[src] || E] @ Wi + bi), direct-reg MFMA --------
__global__ __launch_bounds__(256) void h0_kernel(
    const unsigned short* __restrict__ Vb,   // [NN][LDV] bf16
    const unsigned short* __restrict__ Et,   // [NE][32] bf16 tail (k 128..159)
    const int* __restrict__ src,
    const unsigned short* __restrict__ Bp,   // packed Wi frags (CI chunks)
    const float* __restrict__ bi,
    bf16* __restrict__ H0)
{
  __shared__ float Sb[DH];
  const int tid = threadIdx.x;
  const int e0 = blockIdx.x * MT;
  if (tid < DH) Sb[tid] = bi[tid];
  const int wv = tid >> 6, ln = tid & 15, q = (tid & 63) >> 4;
  const int lane = tid & 63;
  __syncthreads();
  f32x4 acc[NT][2];
#pragma unroll
  for (int t = 0; t < NT; ++t)
#pragma unroll
    for (int m = 0; m < 2; ++m) acc[t][m] = (f32x4){0.f, 0.f, 0.f, 0.f};
  const int r0 = wv * 32 + ln;
  const int s0 = src[e0 + r0], s1 = src[e0 + r0 + 16];
  const unsigned short* v0p = Vb + (size_t)s0 * LDV;
  const unsigned short* v1p = Vb + (size_t)s1 * LDV;
  const unsigned short* bp = Bp + (size_t)lane * 8;
  short8 bfr[NT];
#pragma unroll
  for (int c = 0; c < 4; ++c) {
    short8 a0 = *(const short8*)(v0p + c * 32 + q * 8);
    short8 a1 = *(const short8*)(v1p + c * 32 + q * 8);
#pragma unroll
    for (int t = 0; t < NT; ++t)
      bfr[t] = *(const short8*)(bp + (size_t)(c * NT + t) * 512);
#pragma unroll
    for (int t = 0; t < NT; ++t) {
      acc[t][0] = MFMA(a0, bfr[t], acc[t][0]);
      acc[t][1] = MFMA(a1, bfr[t], acc[t][1]);
    }
  }
  {  // chunk 4: per-edge tail
    short8 a0 = *(const short8*)(Et + (size_t)(e0 + r0) * 32 + q * 8);
    short8 a1 = *(const short8*)(Et + (size_t)(e0 + r0 + 16) * 32 + q * 8);
#pragma unroll
    for (int t = 0; t < NT; ++t)
      bfr[t] = *(const short8*)(bp + (size_t)(4 * NT + t) * 512);
#pragma unroll
    for (int t = 0; t < NT; ++t) {
      acc[t][0] = MFMA(a0, bfr[t], acc[t][0]);
      acc[t][1] = MFMA(a1, bfr[t], acc[t][1]);
    }
  }
#pragma unroll
  for (int t = 0; t < NT; ++t) {
    int c = t * 16 + ln;
    if (c < DH) {
#pragma unroll
      for (int m = 0; m < 2; ++m)
#pragma unroll
        for (int i = 0; i < 4; ++i) {
          int e = e0 + wv * 32 + m * 16 + q * 4 + i;
          float h = acc[t][m][i] + Sb[c];
          H0[(size_t)e * DH + c] = __float2bfloat16(h > 0.f ? h : 0.f);
        }
    }
  }
}

// ------- S[n][0..223] = sum_{j in seg(n)} H[perm[j]][0..199], bf16, pad 0 ----
__global__ __launch_bounds__(256) void gsum_kernel(
    const bf16* __restrict__ H, const int* __restrict__ offsets,
    const int* __restrict__ perm, unsigned short* __restrict__ S)
{
  int t = blockIdx.x * 256 + threadIdx.x;
  if (t >= NN * 28) return;
  int n = t / 28, g = t - n * 28;
  short8 w;
  if (g >= 25) {                 // zero padding cols 200..223
#pragma unroll
    for (int k = 0; k < 8; ++k) w[k] = 0;
    *(short8*)&S[(size_t)n * LDS_ + g * 8] = w;
    return;
  }
  int st = offsets[n], en = offsets[n + 1];
  float a[8];
#pragma unroll
  for (int k = 0; k < 8; ++k) a[k] = 0.f;
  const unsigned short* Hs = (const unsigned short*)H;
  for (int j = st; j < en; ++j) {
    int e = perm[j];
    short8 u = *(const short8*)(Hs + (size_t)e * DH + g * 8);
#pragma unroll
    for (int k = 0; k < 8; ++k) a[k] += us2f((unsigned short)u[k]);
  }
#pragma unroll
  for (int k = 0; k < 8; ++k) w[k] = (short)f2us(a[k]);
  *(short8*)&S[(size_t)n * LDS_ + g * 8] = w;
}

// --- fused MP GEMM: Hout[e] = relu(H0[e] + (S[src[e]] - H[e^1]) @ Wh + bh) ---
// A-op fed as two MFMA accumulations: +S frag, + (sign-flipped H) frag.
__global__ __launch_bounds__(256) void fmp_kernel(
    const bf16* __restrict__ H,              // current layer [NE][200]
    const bf16* H0,                          // h^(0) [NE][200] (may alias Hout)
    const unsigned short* __restrict__ S,    // [NN][224], cols>=200 zero
    const int* __restrict__ src,
    const unsigned short* __restrict__ Bp,   // packed Wh frags (CH chunks)
    const float* __restrict__ bh,
    bf16* Hout)
{
  __shared__ float Sb[DH];
  const int tid = threadIdx.x;
  const int e0 = blockIdx.x * MT;
  if (tid < DH) Sb[tid] = bh[tid];
  const int wv = tid >> 6, ln = tid & 15, q = (tid & 63) >> 4;
  const int lane = tid & 63;
  __syncthreads();
  f32x4 acc[NT][2];
#pragma unroll
  for (int t = 0; t < NT; ++t)
#pragma unroll
    for (int m = 0; m < 2; ++m) acc[t][m] = (f32x4){0.f, 0.f, 0.f, 0.f};
  const int r0 = e0 + wv * 32 + ln, r1 = r0 + 16;
  const int s0 = src[r0], s1 = src[r1];
  const unsigned short* sp0 = S + (size_t)s0 * LDS_;
  const unsigned short* sp1 = S + (size_t)s1 * LDS_;
  const unsigned short* Hs = (const unsigned short*)H;
  const unsigned short* hp0 = Hs + (size_t)(r0 ^ 1) * DH;
  const unsigned short* hp1 = Hs + (size_t)(r1 ^ 1) * DH;
  const unsigned short* bp = Bp + (size_t)lane * 8;
  short8 bfr[NT];
#pragma unroll
  for (int c = 0; c < CH; ++c) {
    // c==6 reads H cols 200..223 past row end: finite bf16, B zero (A*0=0)
    short8 sa0 = *(const short8*)(sp0 + c * 32 + q * 8);
    short8 sa1 = *(const short8*)(sp1 + c * 32 + q * 8);
    short8 na0 = neg8(*(const short8*)(hp0 + c * 32 + q * 8));
    short8 na1 = neg8(*(const short8*)(hp1 + c * 32 + q * 8));
#pragma unroll
    for (int t = 0; t < NT; ++t)
      bfr[t] = *(const short8*)(bp + (size_t)(c * NT + t) * 512);
#pragma unroll
    for (int t = 0; t < NT; ++t) {
      acc[t][0] = MFMA(sa0, bfr[t], acc[t][0]);
      acc[t][0] = MFMA(na0, bfr[t], acc[t][0]);
      acc[t][1] = MFMA(sa1, bfr[t], acc[t][1]);
      acc[t][1] = MFMA(na1, bfr[t], acc[t][1]);
    }
  }
  const unsigned short* H0s = (const unsigned short*)H0;
  unsigned short* Os = (unsigned short*)Hout;
#pragma unroll
  for (int t = 0; t < NT; ++t) {
    int c = t * 16 + ln;
    if (c < DH) {
#pragma unroll
      for (int m = 0; m < 2; ++m)
#pragma unroll
        for (int i = 0; i < 4; ++i) {
          int e = e0 + wv * 32 + m * 16 + q * 4 + i;
          float h = acc[t][m][i] + Sb[c] + us2f(H0s[(size_t)e * DH + c]);
          Os[(size_t)e * DH + c] = f2us(h > 0.f ? h : 0.f);
        }
    }
  }
}

// --- Abuf[n][g*8..] = bf16( sum_{j in seg(n)} H[perm[j]^1] ), cols 0..199 ----
__global__ __launch_bounds__(256) void gather_kernel(
    const bf16* __restrict__ H, const int* __restrict__ offsets,
    const int* __restrict__ perm, int xm, unsigned short* __restrict__ Abuf)
{
  int t = blockIdx.x * 256 + threadIdx.x;
  if (t >= NN * 25) return;
  int n = t / 25, g = t - n * 25;
  int st = offsets[n], en = offsets[n + 1];
  float a[8];
#pragma unroll
  for (int k = 0; k < 8; ++k) a[k] = 0.f;
  const unsigned short* Hs = (const unsigned short*)H;
  for (int j = st; j < en; ++j) {
    int e = perm[j] ^ xm;
    short8 u = *(const short8*)(Hs + (size_t)e * DH + g * 8);
#pragma unroll
    for (int k = 0; k < 8; ++k) a[k] += us2f((unsigned short)u[k]);
  }
  short8 w;
#pragma unroll
  for (int k = 0; k < 8; ++k) w[k] = (short)f2us(a[k]);
  *(short8*)&Abuf[(size_t)n * KO + g * 8] = w;
}

// ------- H_v = relu(A' @ Wo + bo), A' = [Mv || V] packed bf16, fp32 out ------
__global__ __launch_bounds__(256) void out_kernel(
    const unsigned short* __restrict__ Abuf,  // [NNPAD][KO] bf16
    const unsigned short* __restrict__ Bp,    // packed Wo frags (CO chunks)
    const float* __restrict__ bo,
    float* __restrict__ out)
{
  __shared__ float Sb[DH];
  const int tid = threadIdx.x;
  const int n0 = blockIdx.x * MT;
  if (tid < DH) Sb[tid] = bo[tid];
  const int wv = tid >> 6, ln = tid & 15, q = (tid & 63) >> 4;
  const int lane = tid & 63;
  __syncthreads();
  f32x4 acc[NT][2];
#pragma unroll
  for (int t = 0; t < NT; ++t)
#pragma unroll
    for (int m = 0; m < 2; ++m) acc[t][m] = (f32x4){0.f, 0.f, 0.f, 0.f};
  const unsigned short* a0p = Abuf + (size_t)(n0 + wv * 32 + ln) * KO;
  const unsigned short* a1p = a0p + (size_t)16 * KO;
  const unsigned short* bp = Bp + (size_t)lane * 8;
  short8 bfr[NT];
#pragma unroll
  for (int c = 0; c < CO; ++c) {
    short8 a0 = *(const short8*)(a0p + c * 32 + q * 8);
    short8 a1 = *(const short8*)(a1p + c * 32 + q * 8);
#pragma unroll
    for (int t = 0; t < NT; ++t)
      bfr[t] = *(const short8*)(bp + (size_t)(c * NT + t) * 512);
#pragma unroll
    for (int t = 0; t < NT; ++t) {
      acc[t][0] = MFMA(a0, bfr[t], acc[t][0]);
      acc[t][1] = MFMA(a1, bfr[t], acc[t][1]);
    }
  }
#pragma unroll
  for (int t = 0; t < NT; ++t) {
    int c = t * 16 + ln;
    if (c < DH) {
#pragma unroll
      for (int m = 0; m < 2; ++m)
#pragma unroll
        for (int i = 0; i < 4; ++i) {
          int n = n0 + wv * 32 + m * 16 + q * 4 + i;
          if (n < NN) {
            float h = acc[t][m][i] + Sb[c];
            out[(size_t)n * DH + c] = h > 0.f ? h : 0.f;
          }
        }
    }
  }
}

extern "C" void kernel_launch(void* const* d_in, const int* in_sizes, int n_in,
                              void* d_out, int out_size, void* d_ws, size_t ws_size,
                              hipStream_t stream)
{
  const float* V  = (const float*)d_in[0];
  const float* Ef = (const float*)d_in[1];
  const int* eidx = (const int*)d_in[2];   // [2, NE] -> row0 src, row1 dst
  const int* rev  = (const int*)d_in[3];   (void)rev;  // == e^1 (paired layout)
  const float* Wi = (const float*)d_in[4];
  const float* bi = (const float*)d_in[5];
  const float* Wh = (const float*)d_in[6];
  const float* bh = (const float*)d_in[7];
  const float* Wo = (const float*)d_in[8];
  const float* bo = (const float*)d_in[9];
  const int* src = eidx;
  const int* dst = eidx + NE;

  // ws: H0 bf16 160MB | Hb bf16 160MB (Vb16 aliases head) | region3 160MB
  //     (Et [NE][32] -> S [NN][224] -> Abuf [NNPAD][352], sequential reuse)
  //     | CSR | packed weights
  bf16* H0 = (bf16*)d_ws;
  bf16* Hb = H0 + (size_t)NE * DH;
  bf16* R3 = Hb + (size_t)NE * DH;
  unsigned short* Vb16 = (unsigned short*)Hb;  // dead before fmp1 writes Hb
  unsigned short* Et   = (unsigned short*)R3;  // dead after h0
  unsigned short* Sbuf = (unsigned short*)R3;  // live gsum1..fmp2
  unsigned short* Abuf = (unsigned short*)R3;  // live packav..out
  int* counts   = (int*)(R3 + (size_t)NE * DH);
  int* chunkSum = counts + NN;
  int* chunkOff = chunkSum + 1024;
  int* offsets  = chunkOff + 1024;
  int* cursor   = offsets + NN + 1;
  int* perm     = cursor + NN;
  unsigned short* Bpi = (unsigned short*)(((uintptr_t)(perm + NE) + 15) & ~(uintptr_t)15);
  unsigned short* Bph = Bpi + (size_t)CI * 832 * 8;
  unsigned short* Bpo = Bph + (size_t)CH * 832 * 8;

  const int gGE = NE / MT;                 // 3125
  const int gON = (NN + MT - 1) / MT;      // 1563
  const int gE  = (NE + 255) / 256;        // 1563
  const int gN  = (NN + 255) / 256;        // 782
  const int gG  = (NN * 25 + 255) / 256;   // 19532
  const int gS  = (NN * 28 + 255) / 256;   // 21875

  // ---- CSR build (by dst; out-edges of n are in-edges ^1) ----
  hipMemsetAsync(counts, 0, (size_t)NN * sizeof(int), stream);
  hist_kernel<<<gE, 256, 0, stream>>>(dst, counts);
  chunksum_kernel<<<NCH, 256, 0, stream>>>(counts, chunkSum);
  scanchunks_kernel<<<1, 1024, 0, stream>>>(chunkSum, chunkOff);
  scanlocal_kernel<<<gN, 256, 0, stream>>>(counts, chunkOff, offsets, cursor);
  scatter_kernel<<<gE, 256, 0, stream>>>(dst, cursor, perm);

  // ---- packed weights (MFMA fragment order, bf16, zero-padded) ----
  prepwpack_kernel<<<(CI * 832 + 255) / 256, 256, 0, stream>>>(Wi, DV + DE, CI, 0, Bpi);
  prepwpack_kernel<<<(CH * 832 + 255) / 256, 256, 0, stream>>>(Wh, DH, CH, 0, Bph);
  prepwpack_kernel<<<(CO * 832 + 255) / 256, 256, 0, stream>>>(Wo, 0, CO, 1, Bpo);

  // ---- V -> bf16 (into Vb16, aliases Hb; dead before fmp1 writes Hb) ----
  packv_kernel<<<(NN * (LDV / 8) + 255) / 256, 256, 0, stream>>>(V, Vb16);
  // ---- per-edge tail (aliases region3; dead after h0) ----
  packet_kernel<<<(NE * 4 + 255) / 256, 256, 0, stream>>>(V, Ef, src, Et);

  // ---- H = H0 ----
  h0_kernel<<<gGE, 256, 0, stream>>>(Vb16, Et, src, Bpi, bi, H0);

  // iter 1: S = segsum(H0); Hb = relu(H0 + (S[src]-H0[rev])@Wh + bh)
  gsum_kernel<<<gS, 256, 0, stream>>>(H0, offsets, perm, Sbuf);
  fmp_kernel<<<gGE, 256, 0, stream>>>(H0, H0, Sbuf, src, Bph, bh, Hb);

  // iter 2: S = segsum(Hb); H0 <- relu(H0 + (S[src]-Hb[rev])@Wh + bh)
  gsum_kernel<<<gS, 256, 0, stream>>>(Hb, offsets, perm, Sbuf);
  fmp_kernel<<<gGE, 256, 0, stream>>>(Hb, H0, Sbuf, src, Bph, bh, H0);

  // S dead now: fill Abuf(=region3) V-columns + padding
  packav_kernel<<<(NNPAD * (KO / 8) + 255) / 256, 256, 0, stream>>>(V, Abuf);

  // readout: Mv[n] = sum_{dst[e']=n} Hc[e'^1] -> Abuf cols 0..199 (bf16)
  gather_kernel<<<gG, 256, 0, stream>>>(H0, offsets, perm, 1, Abuf);
  out_kernel<<<gON, 256, 0, stream>>>(Abuf, Bpo, bo, (float*)d_out);
}

// Round 5
// 1336.330 us; speedup vs baseline: 1.4143x; 1.4143x over previous
//
#include <hip/hip_runtime.h>
#include <hip/hip_bf16.h>
#include <stdint.h>

typedef __hip_bfloat16 bf16;
typedef __attribute__((ext_vector_type(8))) short short8;
typedef __attribute__((ext_vector_type(4))) float f32x4;

#define NN 200000    // nodes
#define NNPAD 200064 // 1563*128
#define NE 400000    // directed edges
#define DV 133
#define DE 14
#define DH 200
#define MT 128       // M rows per block
#define NT 13        // 13 col tiles of 16 (200 -> 208 padded)
#define NCH 782      // ceil(NN/256) scan chunks

#define CI 5         // K chunks Wi (147 -> 160)
#define CH 7         // K chunks Wh (200 -> 224)
#define CO 11        // K chunks Wo (333 -> 352)
#define KO 352
#define LDV 160      // Vb16 row stride (shorts)

#define MFMA(a, b, c) __builtin_amdgcn_mfma_f32_16x16x32_bf16((a), (b), (c), 0, 0, 0)

__device__ __forceinline__ float us2f(unsigned short u) {
  return __uint_as_float(((unsigned)u) << 16);
}
__device__ __forceinline__ unsigned short f2us(float f) {
  bf16 h = __float2bfloat16(f);
  return *reinterpret_cast<unsigned short*>(&h);
}

// ---- W pack into MFMA-fragment order --------------------------------------
// frag f = ((c*13 + t)*64 + lane); lane = q*16+ln; elem j -> k = c*32+q*8+j,
// col = t*16+ln.  mode 0: W[k][col]; mode 1 (Wo permuted for A'=[Mv||V]):
// W[(k<200)?133+k:k-200][col], valid k<333.
__global__ __launch_bounds__(256) void prepwpack_kernel(
    const float* __restrict__ W, int Ksrc, int nchunks, int mode,
    unsigned short* __restrict__ out)
{
  int f = blockIdx.x * 256 + threadIdx.x;
  int total = nchunks * 13 * 64;
  if (f >= total) return;
  int c = f / 832, rem = f - c * 832;
  int t = rem >> 6, l = rem & 63;
  int q = l >> 4, ln = l & 15;
  int col = t * 16 + ln;
  short8 w;
#pragma unroll
  for (int j = 0; j < 8; ++j) {
    int k = c * 32 + q * 8 + j;
    float v = 0.f;
    if (col < DH) {
      if (mode == 0) {
        if (k < Ksrc) v = W[(size_t)k * DH + col];
      } else {
        if (k < 333) {
          int sr = (k < 200) ? (133 + k) : (k - 200);
          v = W[(size_t)sr * DH + col];
        }
      }
    }
    w[j] = (short)f2us(v);
  }
  *(short8*)&out[(size_t)f * 8] = w;
}

// -------- V -> bf16, padded row stride LDV (cols >= DV zero) -----------------
__global__ __launch_bounds__(256) void packv_kernel(
    const float* __restrict__ V, unsigned short* __restrict__ Vb)
{
  int idx = blockIdx.x * 256 + threadIdx.x;   // one short8 per thread
  if (idx >= NN * (LDV / 8)) return;
  int n = idx / (LDV / 8), g = idx - n * (LDV / 8);
  int k0 = g * 8;
  short8 w;
#pragma unroll
  for (int j = 0; j < 8; ++j) {
    int k = k0 + j;
    float v = (k < DV) ? V[(size_t)n * DV + k] : 0.f;
    w[j] = (short)f2us(v);
  }
  *(short8*)&Vb[(size_t)n * LDV + k0] = w;
}

// ---- per-edge tail for h0 chunk 4: Et[e][0..31] = k 128..159 of [V[src]||Ef]
__global__ __launch_bounds__(256) void packet_kernel(
    const float* __restrict__ V, const float* __restrict__ Ef,
    const int* __restrict__ src, unsigned short* __restrict__ Et)
{
  int idx = blockIdx.x * 256 + threadIdx.x;
  if (idx >= NE * 4) return;
  int e = idx >> 2, part = idx & 3;
  short8 w;
#pragma unroll
  for (int j = 0; j < 8; ++j) w[j] = 0;
  if (part == 0) {
    int s = src[e];
#pragma unroll
    for (int j = 0; j < 5; ++j) w[j] = (short)f2us(V[(size_t)s * DV + 128 + j]);
#pragma unroll
    for (int j = 5; j < 8; ++j) w[j] = (short)f2us(Ef[(size_t)e * DE + (j - 5)]);
  } else if (part == 1) {
#pragma unroll
    for (int j = 0; j < 8; ++j) w[j] = (short)f2us(Ef[(size_t)e * DE + 3 + j]);
  } else if (part == 2) {
#pragma unroll
    for (int j = 0; j < 3; ++j) w[j] = (short)f2us(Ef[(size_t)e * DE + 11 + j]);
  }
  *(short8*)&Et[(size_t)e * 32 + part * 8] = w;
}

// ---- fill Abuf cols 200..351 with bf16(V), zero pad; zero rows >= NN --------
__global__ __launch_bounds__(256) void packav_kernel(
    const float* __restrict__ V, unsigned short* __restrict__ Abuf)
{
  int idx = blockIdx.x * 256 + threadIdx.x;   // one short8 per thread
  if (idx >= NNPAD * (KO / 8)) return;
  int n = idx / (KO / 8), g = idx - n * (KO / 8);
  int k0 = g * 8;
  if (n < NN && k0 < 200) return;             // gather owns these
  short8 w;
#pragma unroll
  for (int j = 0; j < 8; ++j) {
    int k = k0 + j;
    float v = (n < NN && k >= 200 && k < 333) ? V[(size_t)n * DV + (k - 200)] : 0.f;
    w[j] = (short)f2us(v);
  }
  *(short8*)&Abuf[(size_t)n * KO + k0] = w;
}

// ---------------- CSR build: hist -> scan -> scatter --------------------------
__global__ __launch_bounds__(256) void hist_kernel(
    const int* __restrict__ dst, int* __restrict__ counts)
{
  int e = blockIdx.x * 256 + threadIdx.x;
  if (e < NE) atomicAdd(&counts[dst[e]], 1);
}

__global__ __launch_bounds__(256) void chunksum_kernel(
    const int* __restrict__ counts, int* __restrict__ chunkSum)
{
  int b = blockIdx.x, tid = threadIdx.x;
  int i = b * 256 + tid;
  int v = (i < NN) ? counts[i] : 0;
#pragma unroll
  for (int d = 32; d; d >>= 1) v += __shfl_down(v, d, 64);
  __shared__ int ws[4];
  if ((tid & 63) == 0) ws[tid >> 6] = v;
  __syncthreads();
  if (tid == 0) chunkSum[b] = ws[0] + ws[1] + ws[2] + ws[3];
}

__global__ __launch_bounds__(1024) void scanchunks_kernel(
    const int* __restrict__ chunkSum, int* __restrict__ chunkOff)
{
  __shared__ int s[1024];
  int tid = threadIdx.x;
  int v = (tid < NCH) ? chunkSum[tid] : 0;
  s[tid] = v;
  __syncthreads();
  for (int d = 1; d < 1024; d <<= 1) {
    int t = (tid >= d) ? s[tid - d] : 0;
    __syncthreads();
    s[tid] += t;
    __syncthreads();
  }
  if (tid < NCH) chunkOff[tid] = s[tid] - v;  // exclusive
}

__global__ __launch_bounds__(256) void scanlocal_kernel(
    const int* __restrict__ counts, const int* __restrict__ chunkOff,
    int* __restrict__ offsets, int* __restrict__ cursor)
{
  __shared__ int s[256];
  int b = blockIdx.x, tid = threadIdx.x;
  int i = b * 256 + tid;
  int v = (i < NN) ? counts[i] : 0;
  s[tid] = v;
  __syncthreads();
  for (int d = 1; d < 256; d <<= 1) {
    int t = (tid >= d) ? s[tid - d] : 0;
    __syncthreads();
    s[tid] += t;
    __syncthreads();
  }
  if (i < NN) {
    int off = chunkOff[b] + s[tid] - v;
    offsets[i] = off;
    cursor[i] = off;
  }
  if (i == 0) offsets[NN] = NE;
}

__global__ __launch_bounds__(256) void scatter_kernel(
    const int* __restrict__ dst, int* __restrict__ cursor, int* __restrict__ perm)
{
  int e = blockIdx.x * 256 + threadIdx.x;
  if (e < NE) {
    int p = atomicAdd(&cursor[dst[e]], 1);
    perm[p] = e;
  }
}

// ---------------- H0 = relu([V[src] || E] @ Wi + bi), direct-reg MFMA --------
__global__ __launch_bounds__(256) void h0_kernel(
    const unsigned short* __restrict__ Vb,   // [NN][LDV] bf16
    const unsigned short* __restrict__ Et,   // [NE][32] bf16 tail (k 128..159)
    const int* __restrict__ src,
    const unsigned short* __restrict__ Bp,   // packed Wi frags (CI chunks)
    const float* __restrict__ bi,
    bf16* __restrict__ H0)
{
  __shared__ float Sb[DH];
  const int tid = threadIdx.x;
  const int e0 = blockIdx.x * MT;
  if (tid < DH) Sb[tid] = bi[tid];
  const int wv = tid >> 6, ln = tid & 15, q = (tid & 63) >> 4;
  const int lane = tid & 63;
  __syncthreads();
  f32x4 acc[NT][2];
#pragma unroll
  for (int t = 0; t < NT; ++t)
#pragma unroll
    for (int m = 0; m < 2; ++m) acc[t][m] = (f32x4){0.f, 0.f, 0.f, 0.f};
  const int r0 = wv * 32 + ln;
  const int s0 = src[e0 + r0], s1 = src[e0 + r0 + 16];
  const unsigned short* v0p = Vb + (size_t)s0 * LDV;
  const unsigned short* v1p = Vb + (size_t)s1 * LDV;
  const unsigned short* bp = Bp + (size_t)lane * 8;
  short8 bfr[NT];
#pragma unroll
  for (int c = 0; c < 4; ++c) {
    short8 a0 = *(const short8*)(v0p + c * 32 + q * 8);
    short8 a1 = *(const short8*)(v1p + c * 32 + q * 8);
#pragma unroll
    for (int t = 0; t < NT; ++t)
      bfr[t] = *(const short8*)(bp + (size_t)(c * NT + t) * 512);
#pragma unroll
    for (int t = 0; t < NT; ++t) {
      acc[t][0] = MFMA(a0, bfr[t], acc[t][0]);
      acc[t][1] = MFMA(a1, bfr[t], acc[t][1]);
    }
  }
  {  // chunk 4: per-edge tail
    short8 a0 = *(const short8*)(Et + (size_t)(e0 + r0) * 32 + q * 8);
    short8 a1 = *(const short8*)(Et + (size_t)(e0 + r0 + 16) * 32 + q * 8);
#pragma unroll
    for (int t = 0; t < NT; ++t)
      bfr[t] = *(const short8*)(bp + (size_t)(4 * NT + t) * 512);
#pragma unroll
    for (int t = 0; t < NT; ++t) {
      acc[t][0] = MFMA(a0, bfr[t], acc[t][0]);
      acc[t][1] = MFMA(a1, bfr[t], acc[t][1]);
    }
  }
#pragma unroll
  for (int t = 0; t < NT; ++t) {
    int c = t * 16 + ln;
    if (c < DH) {
#pragma unroll
      for (int m = 0; m < 2; ++m)
#pragma unroll
        for (int i = 0; i < 4; ++i) {
          int e = e0 + wv * 32 + m * 16 + q * 4 + i;
          float h = acc[t][m][i] + Sb[c];
          H0[(size_t)e * DH + c] = __float2bfloat16(h > 0.f ? h : 0.f);
        }
    }
  }
}

// ---------------- Q = H @ Wh  (direct-reg, no LDS, no barriers) ---------------
__global__ __launch_bounds__(256) void gemmq_kernel(
    const bf16* __restrict__ H,
    const unsigned short* __restrict__ Bp,   // packed Wh frags (CH chunks)
    bf16* __restrict__ Q)
{
  const int tid = threadIdx.x;
  const int e0 = blockIdx.x * MT;
  const int wv = tid >> 6, ln = tid & 15, q = (tid & 63) >> 4;
  const int lane = tid & 63;
  f32x4 acc[NT][2];
#pragma unroll
  for (int t = 0; t < NT; ++t)
#pragma unroll
    for (int m = 0; m < 2; ++m) acc[t][m] = (f32x4){0.f, 0.f, 0.f, 0.f};
  const unsigned short* Hs = (const unsigned short*)H;
  const unsigned short* a0p = Hs + (size_t)(e0 + wv * 32 + ln) * DH;
  const unsigned short* a1p = a0p + (size_t)16 * DH;
  const unsigned short* bp = Bp + (size_t)lane * 8;
  short8 bfr[NT];
#pragma unroll
  for (int c = 0; c < CH; ++c) {
    // last chunk reads past row end (cols 200..223): B is zero there (A*0=0)
    short8 a0 = *(const short8*)(a0p + c * 32 + q * 8);
    short8 a1 = *(const short8*)(a1p + c * 32 + q * 8);
#pragma unroll
    for (int t = 0; t < NT; ++t)
      bfr[t] = *(const short8*)(bp + (size_t)(c * NT + t) * 512);
#pragma unroll
    for (int t = 0; t < NT; ++t) {
      acc[t][0] = MFMA(a0, bfr[t], acc[t][0]);
      acc[t][1] = MFMA(a1, bfr[t], acc[t][1]);
    }
  }
#pragma unroll
  for (int t = 0; t < NT; ++t) {
    int c = t * 16 + ln;
    if (c < DH) {
#pragma unroll
      for (int m = 0; m < 2; ++m)
#pragma unroll
        for (int i = 0; i < 4; ++i) {
          int e = e0 + wv * 32 + m * 16 + q * 4 + i;
          Q[(size_t)e * DH + c] = __float2bfloat16(acc[t][m][i]);
        }
    }
  }
}

// ------- fused per-node: a = bh + sum_in Q;  Hout[e^1] = relu(H0[e^1]+a-Q[e]) -
// 64 lanes per node: jj = lane>>5 handles edges j = st+jj, st+jj+2, ...;
// g = lane&31 (g<25 active) handles col slice g*8..g*8+7. One shfl_xor(32)
// combines the two jj-half partial sums. Covers every edge exactly once.
// Hout may alias H0 (slice read then written by the same thread, same iter).
__global__ __launch_bounds__(256) void fusedmp_kernel(
    const bf16* __restrict__ Q, const bf16* H0,
    const int* __restrict__ offsets, const int* __restrict__ perm,
    const float* __restrict__ bh, bf16* Hout)
{
  int t = blockIdx.x * 256 + threadIdx.x;
  int n = t >> 6;
  if (n >= NN) return;
  int l = t & 63, jj = l >> 5, g = l & 31;
  const bool act = g < 25;
  int st = offsets[n], en = offsets[n + 1];
  if (st == en) return;
  const unsigned short* Qs = (const unsigned short*)Q;
  const unsigned short* H0s = (const unsigned short*)H0;
  unsigned short* Os = (unsigned short*)Hout;
  float a[8];
#pragma unroll
  for (int k = 0; k < 8; ++k) a[k] = 0.f;
  if (jj == 0 && act) {
    const float4* bp = (const float4*)(bh + g * 8);
    float4 b0 = bp[0], b1 = bp[1];
    a[0] = b0.x; a[1] = b0.y; a[2] = b0.z; a[3] = b0.w;
    a[4] = b1.x; a[5] = b1.y; a[6] = b1.z; a[7] = b1.w;
  }
  for (int j = st + jj; j < en; j += 2) {
    int e = perm[j];
    if (act) {
      short8 u = *(const short8*)(Qs + (size_t)e * DH + g * 8);
#pragma unroll
      for (int k = 0; k < 8; ++k) a[k] += us2f((unsigned short)u[k]);
    }
  }
#pragma unroll
  for (int k = 0; k < 8; ++k) a[k] += __shfl_xor(a[k], 32, 64);
  for (int j = st + jj; j < en; j += 2) {
    int e = perm[j];           // in-edge of n
    int eo = e ^ 1;            // out-edge of n: src[eo]=n, rev[eo]=e
    if (act) {
      short8 uq = *(const short8*)(Qs + (size_t)e * DH + g * 8);   // L1/L2 hit
      short8 uh = *(const short8*)(H0s + (size_t)eo * DH + g * 8);
      short8 w;
#pragma unroll
      for (int k = 0; k < 8; ++k) {
        float h = a[k] - us2f((unsigned short)uq[k]) + us2f((unsigned short)uh[k]);
        w[k] = (short)f2us(h > 0.f ? h : 0.f);
      }
      *(short8*)(Os + (size_t)eo * DH + g * 8) = w;
    }
  }
}

// --- Abuf[n][g*8..] = bf16( sum_{j in seg(n)} H[perm[j]^xm] ), cols 0..199 ---
// Same 64-lane-per-node / 2-edge-ILP layout as fusedmp.
__global__ __launch_bounds__(256) void gather_kernel(
    const bf16* __restrict__ H, const int* __restrict__ offsets,
    const int* __restrict__ perm, int xm, unsigned short* __restrict__ Abuf)
{
  int t = blockIdx.x * 256 + threadIdx.x;
  int n = t >> 6;
  if (n >= NN) return;
  int l = t & 63, jj = l >> 5, g = l & 31;
  const bool act = g < 25;
  int st = offsets[n], en = offsets[n + 1];
  float a[8];
#pragma unroll
  for (int k = 0; k < 8; ++k) a[k] = 0.f;
  const unsigned short* Hs = (const unsigned short*)H;
  for (int j = st + jj; j < en; j += 2) {
    int e = perm[j] ^ xm;
    if (act) {
      short8 u = *(const short8*)(Hs + (size_t)e * DH + g * 8);
#pragma unroll
      for (int k = 0; k < 8; ++k) a[k] += us2f((unsigned short)u[k]);
    }
  }
#pragma unroll
  for (int k = 0; k < 8; ++k) a[k] += __shfl_xor(a[k], 32, 64);
  if (jj == 0 && act) {
    short8 w;
#pragma unroll
    for (int k = 0; k < 8; ++k) w[k] = (short)f2us(a[k]);
    *(short8*)&Abuf[(size_t)n * KO + g * 8] = w;
  }
}

// ------- H_v = relu(A' @ Wo + bo), A' = [Mv || V] packed bf16, fp32 out ------
__global__ __launch_bounds__(256) void out_kernel(
    const unsigned short* __restrict__ Abuf,  // [NNPAD][KO] bf16
    const unsigned short* __restrict__ Bp,    // packed Wo frags (CO chunks)
    const float* __restrict__ bo,
    float* __restrict__ out)
{
  __shared__ float Sb[DH];
  const int tid = threadIdx.x;
  const int n0 = blockIdx.x * MT;
  if (tid < DH) Sb[tid] = bo[tid];
  const int wv = tid >> 6, ln = tid & 15, q = (tid & 63) >> 4;
  const int lane = tid & 63;
  __syncthreads();
  f32x4 acc[NT][2];
#pragma unroll
  for (int t = 0; t < NT; ++t)
#pragma unroll
    for (int m = 0; m < 2; ++m) acc[t][m] = (f32x4){0.f, 0.f, 0.f, 0.f};
  const unsigned short* a0p = Abuf + (size_t)(n0 + wv * 32 + ln) * KO;
  const unsigned short* a1p = a0p + (size_t)16 * KO;
  const unsigned short* bp = Bp + (size_t)lane * 8;
  short8 bfr[NT];
#pragma unroll
  for (int c = 0; c < CO; ++c) {
    short8 a0 = *(const short8*)(a0p + c * 32 + q * 8);
    short8 a1 = *(const short8*)(a1p + c * 32 + q * 8);
#pragma unroll
    for (int t = 0; t < NT; ++t)
      bfr[t] = *(const short8*)(bp + (size_t)(c * NT + t) * 512);
#pragma unroll
    for (int t = 0; t < NT; ++t) {
      acc[t][0] = MFMA(a0, bfr[t], acc[t][0]);
      acc[t][1] = MFMA(a1, bfr[t], acc[t][1]);
    }
  }
#pragma unroll
  for (int t = 0; t < NT; ++t) {
    int c = t * 16 + ln;
    if (c < DH) {
#pragma unroll
      for (int m = 0; m < 2; ++m)
#pragma unroll
        for (int i = 0; i < 4; ++i) {
          int n = n0 + wv * 32 + m * 16 + q * 4 + i;
          if (n < NN) {
            float h = acc[t][m][i] + Sb[c];
            out[(size_t)n * DH + c] = h > 0.f ? h : 0.f;
          }
        }
    }
  }
}

extern "C" void kernel_launch(void* const* d_in, const int* in_sizes, int n_in,
                              void* d_out, int out_size, void* d_ws, size_t ws_size,
                              hipStream_t stream)
{
  const float* V  = (const float*)d_in[0];
  const float* Ef = (const float*)d_in[1];
  const int* eidx = (const int*)d_in[2];   // [2, NE] -> row0 src, row1 dst
  const int* rev  = (const int*)d_in[3];   (void)rev;  // == e^1 (paired layout)
  const float* Wi = (const float*)d_in[4];
  const float* bi = (const float*)d_in[5];
  const float* Wh = (const float*)d_in[6];
  const float* bh = (const float*)d_in[7];
  const float* Wo = (const float*)d_in[8];
  const float* bo = (const float*)d_in[9];
  const int* src = eidx;
  const int* dst = eidx + NE;

  // ws: H0 bf16 160MB | Hb bf16 160MB (Vb16 aliases head) | Q bf16 160MB
  //     (Et / Abuf alias Q) | CSR + packed weights
  bf16* H0 = (bf16*)d_ws;
  bf16* Hb = H0 + (size_t)NE * DH;
  bf16* Q  = Hb + (size_t)NE * DH;
  unsigned short* Vb16 = (unsigned short*)Hb;  // [NN][LDV], dead before fusedmp1
  unsigned short* Et   = (unsigned short*)Q;   // [NE][32], dead after h0
  unsigned short* Abuf = (unsigned short*)Q;   // [NNPAD][KO], alive after fusedmp2
  int* counts   = (int*)(Q + (size_t)NE * DH);
  int* chunkSum = counts + NN;
  int* chunkOff = chunkSum + 1024;
  int* offsets  = chunkOff + 1024;
  int* cursor   = offsets + NN + 1;
  int* perm     = cursor + NN;
  unsigned short* Bpi = (unsigned short*)(((uintptr_t)(perm + NE) + 15) & ~(uintptr_t)15);
  unsigned short* Bph = Bpi + (size_t)CI * 832 * 8;
  unsigned short* Bpo = Bph + (size_t)CH * 832 * 8;

  const int gGE = NE / MT;                 // 3125
  const int gON = (NN + MT - 1) / MT;      // 1563
  const int gE  = (NE + 255) / 256;        // 1563
  const int gN  = (NN + 255) / 256;        // 782
  const int gGF = (NN * 64 + 255) / 256;   // 50000 (64 lanes per node)

  // ---- CSR build (by dst; out-edges of n are in-edges ^1) ----
  hipMemsetAsync(counts, 0, (size_t)NN * sizeof(int), stream);
  hist_kernel<<<gE, 256, 0, stream>>>(dst, counts);
  chunksum_kernel<<<NCH, 256, 0, stream>>>(counts, chunkSum);
  scanchunks_kernel<<<1, 1024, 0, stream>>>(chunkSum, chunkOff);
  scanlocal_kernel<<<gN, 256, 0, stream>>>(counts, chunkOff, offsets, cursor);
  scatter_kernel<<<gE, 256, 0, stream>>>(dst, cursor, perm);

  // ---- packed weights (MFMA fragment order, bf16, zero-padded) ----
  prepwpack_kernel<<<(CI * 832 + 255) / 256, 256, 0, stream>>>(Wi, DV + DE, CI, 0, Bpi);
  prepwpack_kernel<<<(CH * 832 + 255) / 256, 256, 0, stream>>>(Wh, DH, CH, 0, Bph);
  prepwpack_kernel<<<(CO * 832 + 255) / 256, 256, 0, stream>>>(Wo, 0, CO, 1, Bpo);

  // ---- V -> bf16 (into Vb16, aliases Hb; dead before fusedmp1 writes Hb) ----
  packv_kernel<<<(NN * (LDV / 8) + 255) / 256, 256, 0, stream>>>(V, Vb16);
  // ---- per-edge tail (aliases Q; dead before gemmq1 writes Q) ----
  packet_kernel<<<(NE * 4 + 255) / 256, 256, 0, stream>>>(V, Ef, src, Et);

  // ---- H = H0 ----
  h0_kernel<<<gGE, 256, 0, stream>>>(Vb16, Et, src, Bpi, bi, H0);

  // iter 1: Q = H0@Wh; Hb = relu(H0 + segsumQ[src] - Q[rev] + bh)
  gemmq_kernel<<<gGE, 256, 0, stream>>>(H0, Bph, Q);
  fusedmp_kernel<<<gGF, 256, 0, stream>>>(Q, H0, offsets, perm, bh, Hb);

  // iter 2: Q = Hb@Wh; Hc(=H0) = relu(H0 + segsumQ[src] - Q[rev] + bh)
  gemmq_kernel<<<gGE, 256, 0, stream>>>(Hb, Bph, Q);
  fusedmp_kernel<<<gGF, 256, 0, stream>>>(Q, H0, offsets, perm, bh, H0);

  // Q is dead now: fill Abuf(=Q) V-columns + padding
  packav_kernel<<<(NNPAD * (KO / 8) + 255) / 256, 256, 0, stream>>>(V, Abuf);

  // readout: Mv[n] = sum_{dst[e']=n} Hc[e'^1] -> Abuf cols 0..199 (bf16)
  gather_kernel<<<gGF, 256, 0, stream>>>(H0, offsets, perm, 1, Abuf);
  out_kernel<<<gON, 256, 0, stream>>>(Abuf, Bpo, bo, (float*)d_out);
}

// Round 6
// 1237.376 us; speedup vs baseline: 1.5275x; 1.0800x over previous
//
#include <hip/hip_runtime.h>
#include <hip/hip_bf16.h>
#include <stdint.h>

typedef __hip_bfloat16 bf16;
typedef __attribute__((ext_vector_type(8))) short short8;
typedef __attribute__((ext_vector_type(4))) float f32x4;

#define NN 200000    // nodes
#define NNPAD 200064 // 1563*128
#define NE 400000    // directed edges
#define DV 133
#define DE 14
#define DH 200
#define MT 128       // M rows per block
#define NT 13        // 13 col tiles of 16 (200 -> 208 padded)
#define NCH 782      // ceil(NN/256) scan chunks

#define CI 5         // K chunks Wi (147 -> 160)
#define CH 7         // K chunks Wh (200 -> 224)
#define CO 11        // K chunks Wo (333 -> 352)
#define KO 352
#define LDV 160      // Vb16 row stride (shorts)

#define MFMA(a, b, c) __builtin_amdgcn_mfma_f32_16x16x32_bf16((a), (b), (c), 0, 0, 0)

__device__ __forceinline__ float us2f(unsigned short u) {
  return __uint_as_float(((unsigned)u) << 16);
}
__device__ __forceinline__ unsigned short f2us(float f) {
  bf16 h = __float2bfloat16(f);
  return *reinterpret_cast<unsigned short*>(&h);
}

// ---- W pack into MFMA-fragment order --------------------------------------
__global__ __launch_bounds__(256) void prepwpack_kernel(
    const float* __restrict__ W, int Ksrc, int nchunks, int mode,
    unsigned short* __restrict__ out)
{
  int f = blockIdx.x * 256 + threadIdx.x;
  int total = nchunks * 13 * 64;
  if (f >= total) return;
  int c = f / 832, rem = f - c * 832;
  int t = rem >> 6, l = rem & 63;
  int q = l >> 4, ln = l & 15;
  int col = t * 16 + ln;
  short8 w;
#pragma unroll
  for (int j = 0; j < 8; ++j) {
    int k = c * 32 + q * 8 + j;
    float v = 0.f;
    if (col < DH) {
      if (mode == 0) {
        if (k < Ksrc) v = W[(size_t)k * DH + col];
      } else {
        if (k < 333) {
          int sr = (k < 200) ? (133 + k) : (k - 200);
          v = W[(size_t)sr * DH + col];
        }
      }
    }
    w[j] = (short)f2us(v);
  }
  *(short8*)&out[(size_t)f * 8] = w;
}

// -------- V -> bf16, padded row stride LDV (cols >= DV zero) -----------------
__global__ __launch_bounds__(256) void packv_kernel(
    const float* __restrict__ V, unsigned short* __restrict__ Vb)
{
  int idx = blockIdx.x * 256 + threadIdx.x;   // one short8 per thread
  if (idx >= NN * (LDV / 8)) return;
  int n = idx / (LDV / 8), g = idx - n * (LDV / 8);
  int k0 = g * 8;
  short8 w;
#pragma unroll
  for (int j = 0; j < 8; ++j) {
    int k = k0 + j;
    float v = (k < DV) ? V[(size_t)n * DV + k] : 0.f;
    w[j] = (short)f2us(v);
  }
  *(short8*)&Vb[(size_t)n * LDV + k0] = w;
}

// ---- per-position tail for h0 chunk 4: Et[p][0..31] = k 128..159 of
// [V[src[perm[p]]] || Ef[perm[p]]]
__global__ __launch_bounds__(256) void packet_kernel(
    const float* __restrict__ V, const float* __restrict__ Ef,
    const int* __restrict__ perm, const int* __restrict__ psrc,
    unsigned short* __restrict__ Et)
{
  int idx = blockIdx.x * 256 + threadIdx.x;
  if (idx >= NE * 4) return;
  int p = idx >> 2, part = idx & 3;
  int e = perm[p];
  short8 w;
#pragma unroll
  for (int j = 0; j < 8; ++j) w[j] = 0;
  if (part == 0) {
    int s = psrc[p];
#pragma unroll
    for (int j = 0; j < 5; ++j) w[j] = (short)f2us(V[(size_t)s * DV + 128 + j]);
#pragma unroll
    for (int j = 5; j < 8; ++j) w[j] = (short)f2us(Ef[(size_t)e * DE + (j - 5)]);
  } else if (part == 1) {
#pragma unroll
    for (int j = 0; j < 8; ++j) w[j] = (short)f2us(Ef[(size_t)e * DE + 3 + j]);
  } else if (part == 2) {
#pragma unroll
    for (int j = 0; j < 3; ++j) w[j] = (short)f2us(Ef[(size_t)e * DE + 11 + j]);
  }
  *(short8*)&Et[(size_t)p * 32 + part * 8] = w;
}

// ---- fill Abuf cols 200..351 with bf16(V), zero pad; zero rows >= NN --------
__global__ __launch_bounds__(256) void packav_kernel(
    const float* __restrict__ V, unsigned short* __restrict__ Abuf)
{
  int idx = blockIdx.x * 256 + threadIdx.x;   // one short8 per thread
  if (idx >= NNPAD * (KO / 8)) return;
  int n = idx / (KO / 8), g = idx - n * (KO / 8);
  int k0 = g * 8;
  if (n < NN && k0 < 200) return;             // gather owns these
  short8 w;
#pragma unroll
  for (int j = 0; j < 8; ++j) {
    int k = k0 + j;
    float v = (n < NN && k >= 200 && k < 333) ? V[(size_t)n * DV + (k - 200)] : 0.f;
    w[j] = (short)f2us(v);
  }
  *(short8*)&Abuf[(size_t)n * KO + k0] = w;
}

// ---------------- CSR build: hist -> scan -> scatter --------------------------
__global__ __launch_bounds__(256) void hist_kernel(
    const int* __restrict__ dst, int* __restrict__ counts)
{
  int e = blockIdx.x * 256 + threadIdx.x;
  if (e < NE) atomicAdd(&counts[dst[e]], 1);
}

__global__ __launch_bounds__(256) void chunksum_kernel(
    const int* __restrict__ counts, int* __restrict__ chunkSum)
{
  int b = blockIdx.x, tid = threadIdx.x;
  int i = b * 256 + tid;
  int v = (i < NN) ? counts[i] : 0;
#pragma unroll
  for (int d = 32; d; d >>= 1) v += __shfl_down(v, d, 64);
  __shared__ int ws[4];
  if ((tid & 63) == 0) ws[tid >> 6] = v;
  __syncthreads();
  if (tid == 0) chunkSum[b] = ws[0] + ws[1] + ws[2] + ws[3];
}

__global__ __launch_bounds__(1024) void scanchunks_kernel(
    const int* __restrict__ chunkSum, int* __restrict__ chunkOff)
{
  __shared__ int s[1024];
  int tid = threadIdx.x;
  int v = (tid < NCH) ? chunkSum[tid] : 0;
  s[tid] = v;
  __syncthreads();
  for (int d = 1; d < 1024; d <<= 1) {
    int t = (tid >= d) ? s[tid - d] : 0;
    __syncthreads();
    s[tid] += t;
    __syncthreads();
  }
  if (tid < NCH) chunkOff[tid] = s[tid] - v;  // exclusive
}

__global__ __launch_bounds__(256) void scanlocal_kernel(
    const int* __restrict__ counts, const int* __restrict__ chunkOff,
    int* __restrict__ offsets, int* __restrict__ cursor)
{
  __shared__ int s[256];
  int b = blockIdx.x, tid = threadIdx.x;
  int i = b * 256 + tid;
  int v = (i < NN) ? counts[i] : 0;
  s[tid] = v;
  __syncthreads();
  for (int d = 1; d < 256; d <<= 1) {
    int t = (tid >= d) ? s[tid - d] : 0;
    __syncthreads();
    s[tid] += t;
    __syncthreads();
  }
  if (i < NN) {
    int off = chunkOff[b] + s[tid] - v;
    offsets[i] = off;
    cursor[i] = off;
  }
  if (i == 0) offsets[NN] = NE;
}

__global__ __launch_bounds__(256) void scatter_kernel(
    const int* __restrict__ dst, int* __restrict__ cursor, int* __restrict__ perm)
{
  int e = blockIdx.x * 256 + threadIdx.x;
  if (e < NE) {
    int p = atomicAdd(&cursor[dst[e]], 1);
    perm[p] = e;
  }
}

// ---- ipos[perm[p]] = p ------------------------------------------------------
__global__ __launch_bounds__(256) void invperm_kernel(
    const int* __restrict__ perm, int* __restrict__ ipos)
{
  int p = blockIdx.x * 256 + threadIdx.x;
  if (p < NE) ipos[perm[p]] = p;
}

// ---- rpos[p] = ipos[perm[p]^1]; psrc[p] = src[perm[p]] ----------------------
__global__ __launch_bounds__(256) void rpos_kernel(
    const int* __restrict__ perm, const int* __restrict__ ipos,
    const int* __restrict__ src, int* __restrict__ rpos, int* __restrict__ psrc)
{
  int p = blockIdx.x * 256 + threadIdx.x;
  if (p < NE) {
    int e = perm[p];
    rpos[p] = ipos[e ^ 1];
    psrc[p] = src[e];
  }
}

// ------- H0p[p] = relu([V[psrc[p]] || E[perm[p]]] @ Wi + bi), bf16 -----------
__global__ __launch_bounds__(256) void h0_kernel(
    const unsigned short* __restrict__ Vb,   // [NN][LDV] bf16
    const unsigned short* __restrict__ Et,   // [NE][32] bf16 tail (k 128..159)
    const int* __restrict__ psrc,
    const unsigned short* __restrict__ Bp,   // packed Wi frags (CI chunks)
    const float* __restrict__ bi,
    bf16* __restrict__ H0)
{
  __shared__ float Sb[DH];
  const int tid = threadIdx.x;
  const int e0 = blockIdx.x * MT;
  if (tid < DH) Sb[tid] = bi[tid];
  const int wv = tid >> 6, ln = tid & 15, q = (tid & 63) >> 4;
  const int lane = tid & 63;
  __syncthreads();
  f32x4 acc[NT][2];
#pragma unroll
  for (int t = 0; t < NT; ++t)
#pragma unroll
    for (int m = 0; m < 2; ++m) acc[t][m] = (f32x4){0.f, 0.f, 0.f, 0.f};
  const int r0 = wv * 32 + ln;
  const int s0 = psrc[e0 + r0], s1 = psrc[e0 + r0 + 16];
  const unsigned short* v0p = Vb + (size_t)s0 * LDV;
  const unsigned short* v1p = Vb + (size_t)s1 * LDV;
  const unsigned short* bp = Bp + (size_t)lane * 8;
  short8 bfr[NT];
#pragma unroll
  for (int c = 0; c < 4; ++c) {
    short8 a0 = *(const short8*)(v0p + c * 32 + q * 8);
    short8 a1 = *(const short8*)(v1p + c * 32 + q * 8);
#pragma unroll
    for (int t = 0; t < NT; ++t)
      bfr[t] = *(const short8*)(bp + (size_t)(c * NT + t) * 512);
#pragma unroll
    for (int t = 0; t < NT; ++t) {
      acc[t][0] = MFMA(a0, bfr[t], acc[t][0]);
      acc[t][1] = MFMA(a1, bfr[t], acc[t][1]);
    }
  }
  {  // chunk 4: per-position tail
    short8 a0 = *(const short8*)(Et + (size_t)(e0 + r0) * 32 + q * 8);
    short8 a1 = *(const short8*)(Et + (size_t)(e0 + r0 + 16) * 32 + q * 8);
#pragma unroll
    for (int t = 0; t < NT; ++t)
      bfr[t] = *(const short8*)(bp + (size_t)(4 * NT + t) * 512);
#pragma unroll
    for (int t = 0; t < NT; ++t) {
      acc[t][0] = MFMA(a0, bfr[t], acc[t][0]);
      acc[t][1] = MFMA(a1, bfr[t], acc[t][1]);
    }
  }
#pragma unroll
  for (int t = 0; t < NT; ++t) {
    int c = t * 16 + ln;
    if (c < DH) {
#pragma unroll
      for (int m = 0; m < 2; ++m)
#pragma unroll
        for (int i = 0; i < 4; ++i) {
          int e = e0 + wv * 32 + m * 16 + q * 4 + i;
          float h = acc[t][m][i] + Sb[c];
          H0[(size_t)e * DH + c] = __float2bfloat16(h > 0.f ? h : 0.f);
        }
    }
  }
}

// ---------------- Q = H @ Wh  (direct-reg, no LDS, no barriers) ---------------
__global__ __launch_bounds__(256) void gemmq_kernel(
    const bf16* __restrict__ H,
    const unsigned short* __restrict__ Bp,   // packed Wh frags (CH chunks)
    bf16* __restrict__ Q)
{
  const int tid = threadIdx.x;
  const int e0 = blockIdx.x * MT;
  const int wv = tid >> 6, ln = tid & 15, q = (tid & 63) >> 4;
  const int lane = tid & 63;
  f32x4 acc[NT][2];
#pragma unroll
  for (int t = 0; t < NT; ++t)
#pragma unroll
    for (int m = 0; m < 2; ++m) acc[t][m] = (f32x4){0.f, 0.f, 0.f, 0.f};
  const unsigned short* Hs = (const unsigned short*)H;
  const unsigned short* a0p = Hs + (size_t)(e0 + wv * 32 + ln) * DH;
  const unsigned short* a1p = a0p + (size_t)16 * DH;
  const unsigned short* bp = Bp + (size_t)lane * 8;
  short8 bfr[NT];
#pragma unroll
  for (int c = 0; c < CH; ++c) {
    // last chunk reads past row end (cols 200..223): B is zero there (A*0=0)
    short8 a0 = *(const short8*)(a0p + c * 32 + q * 8);
    short8 a1 = *(const short8*)(a1p + c * 32 + q * 8);
#pragma unroll
    for (int t = 0; t < NT; ++t)
      bfr[t] = *(const short8*)(bp + (size_t)(c * NT + t) * 512);
#pragma unroll
    for (int t = 0; t < NT; ++t) {
      acc[t][0] = MFMA(a0, bfr[t], acc[t][0]);
      acc[t][1] = MFMA(a1, bfr[t], acc[t][1]);
    }
  }
#pragma unroll
  for (int t = 0; t < NT; ++t) {
    int c = t * 16 + ln;
    if (c < DH) {
#pragma unroll
      for (int m = 0; m < 2; ++m)
#pragma unroll
        for (int i = 0; i < 4; ++i) {
          int e = e0 + wv * 32 + m * 16 + q * 4 + i;
          Q[(size_t)e * DH + c] = __float2bfloat16(acc[t][m][i]);
        }
    }
  }
}

// ------- fused per-node (perm-ordered storage):
// a = bh + sum_{p in seg(n)} Qp[p]   (SEQUENTIAL rows)
// for p in seg(n): rp = rpos[p];
//   val = relu(H0p[rp] + a - Qp[p]); write at (seqout? p : rp)
__global__ __launch_bounds__(256) void fusedmp_kernel(
    const bf16* __restrict__ Q, const bf16* __restrict__ H0,
    const int* __restrict__ offsets, const int* __restrict__ rpos,
    const float* __restrict__ bh, int seqout, bf16* __restrict__ Hout)
{
  int t = blockIdx.x * 256 + threadIdx.x;
  if (t >= NN * 25) return;
  int n = t / 25, g = t - n * 25;
  int st = offsets[n], en = offsets[n + 1];
  if (st == en) return;
  const unsigned short* Qs = (const unsigned short*)Q;
  const unsigned short* H0s = (const unsigned short*)H0;
  unsigned short* Os = (unsigned short*)Hout;
  float a[8];
  const float4* bp = (const float4*)(bh + g * 8);
  float4 b0 = bp[0], b1 = bp[1];
  a[0] = b0.x; a[1] = b0.y; a[2] = b0.z; a[3] = b0.w;
  a[4] = b1.x; a[5] = b1.y; a[6] = b1.z; a[7] = b1.w;
  for (int p = st; p < en; ++p) {               // sequential rows
    short8 u = *(const short8*)(Qs + (size_t)p * DH + g * 8);
#pragma unroll
    for (int k = 0; k < 8; ++k) a[k] += us2f((unsigned short)u[k]);
  }
  for (int p = st; p < en; ++p) {
    int rp = rpos[p];
    short8 uq = *(const short8*)(Qs + (size_t)p * DH + g * 8);    // L1 hit
    short8 uh = *(const short8*)(H0s + (size_t)rp * DH + g * 8);  // random row
    short8 w;
#pragma unroll
    for (int k = 0; k < 8; ++k) {
      float h = a[k] - us2f((unsigned short)uq[k]) + us2f((unsigned short)uh[k]);
      w[k] = (short)f2us(h > 0.f ? h : 0.f);
    }
    *(short8*)(Os + (size_t)(seqout ? p : rp) * DH + g * 8) = w;
  }
}

// --- Abuf[n][g*8..] = bf16( sum_{p in seg(n)} Hrev[p] )  -- fully sequential -
__global__ __launch_bounds__(256) void gatherseq_kernel(
    const bf16* __restrict__ Hrev, const int* __restrict__ offsets,
    unsigned short* __restrict__ Abuf)
{
  int t = blockIdx.x * 256 + threadIdx.x;
  if (t >= NN * 25) return;
  int n = t / 25, g = t - n * 25;
  int st = offsets[n], en = offsets[n + 1];
  float a[8];
#pragma unroll
  for (int k = 0; k < 8; ++k) a[k] = 0.f;
  const unsigned short* Hs = (const unsigned short*)Hrev;
  for (int p = st; p < en; ++p) {
    short8 u = *(const short8*)(Hs + (size_t)p * DH + g * 8);
#pragma unroll
    for (int k = 0; k < 8; ++k) a[k] += us2f((unsigned short)u[k]);
  }
  short8 w;
#pragma unroll
  for (int k = 0; k < 8; ++k) w[k] = (short)f2us(a[k]);
  *(short8*)&Abuf[(size_t)n * KO + g * 8] = w;
}

// ------- H_v = relu(A' @ Wo + bo), A' = [Mv || V] packed bf16, fp32 out ------
__global__ __launch_bounds__(256) void out_kernel(
    const unsigned short* __restrict__ Abuf,  // [NNPAD][KO] bf16
    const unsigned short* __restrict__ Bp,    // packed Wo frags (CO chunks)
    const float* __restrict__ bo,
    float* __restrict__ out)
{
  __shared__ float Sb[DH];
  const int tid = threadIdx.x;
  const int n0 = blockIdx.x * MT;
  if (tid < DH) Sb[tid] = bo[tid];
  const int wv = tid >> 6, ln = tid & 15, q = (tid & 63) >> 4;
  const int lane = tid & 63;
  __syncthreads();
  f32x4 acc[NT][2];
#pragma unroll
  for (int t = 0; t < NT; ++t)
#pragma unroll
    for (int m = 0; m < 2; ++m) acc[t][m] = (f32x4){0.f, 0.f, 0.f, 0.f};
  const unsigned short* a0p = Abuf + (size_t)(n0 + wv * 32 + ln) * KO;
  const unsigned short* a1p = a0p + (size_t)16 * KO;
  const unsigned short* bp = Bp + (size_t)lane * 8;
  short8 bfr[NT];
#pragma unroll
  for (int c = 0; c < CO; ++c) {
    short8 a0 = *(const short8*)(a0p + c * 32 + q * 8);
    short8 a1 = *(const short8*)(a1p + c * 32 + q * 8);
#pragma unroll
    for (int t = 0; t < NT; ++t)
      bfr[t] = *(const short8*)(bp + (size_t)(c * NT + t) * 512);
#pragma unroll
    for (int t = 0; t < NT; ++t) {
      acc[t][0] = MFMA(a0, bfr[t], acc[t][0]);
      acc[t][1] = MFMA(a1, bfr[t], acc[t][1]);
    }
  }
#pragma unroll
  for (int t = 0; t < NT; ++t) {
    int c = t * 16 + ln;
    if (c < DH) {
#pragma unroll
      for (int m = 0; m < 2; ++m)
#pragma unroll
        for (int i = 0; i < 4; ++i) {
          int n = n0 + wv * 32 + m * 16 + q * 4 + i;
          if (n < NN) {
            float h = acc[t][m][i] + Sb[c];
            out[(size_t)n * DH + c] = h > 0.f ? h : 0.f;
          }
        }
    }
  }
}

extern "C" void kernel_launch(void* const* d_in, const int* in_sizes, int n_in,
                              void* d_out, int out_size, void* d_ws, size_t ws_size,
                              hipStream_t stream)
{
  const float* V  = (const float*)d_in[0];
  const float* Ef = (const float*)d_in[1];
  const int* eidx = (const int*)d_in[2];   // [2, NE] -> row0 src, row1 dst
  const int* rev  = (const int*)d_in[3];   (void)rev;  // == e^1 (paired layout)
  const float* Wi = (const float*)d_in[4];
  const float* bi = (const float*)d_in[5];
  const float* Wh = (const float*)d_in[6];
  const float* bh = (const float*)d_in[7];
  const float* Wo = (const float*)d_in[8];
  const float* bo = (const float*)d_in[9];
  const int* src = eidx;
  const int* dst = eidx + NE;

  // ws: H0p 160MB | Hbp 160MB (Vb16 aliases head; Hrev reuses after gemmq2)
  //     | Q 160MB (Et / Abuf alias) | CSR + rpos/psrc + packed weights
  bf16* H0 = (bf16*)d_ws;
  bf16* Hb = H0 + (size_t)NE * DH;
  bf16* Q  = Hb + (size_t)NE * DH;
  unsigned short* Vb16 = (unsigned short*)Hb;  // dead before fusedmp1 writes Hb
  bf16* Hrev = Hb;                             // iter2 out (Hb dead after gemmq2)
  unsigned short* Et   = (unsigned short*)Q;   // dead after h0
  unsigned short* Abuf = (unsigned short*)Q;   // alive after fusedmp2
  int* counts   = (int*)(Q + (size_t)NE * DH);
  int* chunkSum = counts + NN;
  int* chunkOff = chunkSum + 1024;
  int* offsets  = chunkOff + 1024;
  int* cursor   = offsets + NN + 1;
  int* perm     = cursor + NN;
  int* ipos     = perm + NE;
  int* rpos     = ipos + NE;
  int* psrc     = rpos + NE;
  unsigned short* Bpi = (unsigned short*)(((uintptr_t)(psrc + NE) + 15) & ~(uintptr_t)15);
  unsigned short* Bph = Bpi + (size_t)CI * 832 * 8;
  unsigned short* Bpo = Bph + (size_t)CH * 832 * 8;

  const int gGE = NE / MT;                 // 3125
  const int gON = (NN + MT - 1) / MT;      // 1563
  const int gE  = (NE + 255) / 256;        // 1563
  const int gN  = (NN + 255) / 256;        // 782
  const int gG  = (NN * 25 + 255) / 256;   // 19532

  // ---- CSR build (by dst; out-edges of n are in-edges ^1) ----
  hipMemsetAsync(counts, 0, (size_t)NN * sizeof(int), stream);
  hist_kernel<<<gE, 256, 0, stream>>>(dst, counts);
  chunksum_kernel<<<NCH, 256, 0, stream>>>(counts, chunkSum);
  scanchunks_kernel<<<1, 1024, 0, stream>>>(chunkSum, chunkOff);
  scanlocal_kernel<<<gN, 256, 0, stream>>>(counts, chunkOff, offsets, cursor);
  scatter_kernel<<<gE, 256, 0, stream>>>(dst, cursor, perm);
  invperm_kernel<<<gE, 256, 0, stream>>>(perm, ipos);
  rpos_kernel<<<gE, 256, 0, stream>>>(perm, ipos, src, rpos, psrc);

  // ---- packed weights (MFMA fragment order, bf16, zero-padded) ----
  prepwpack_kernel<<<(CI * 832 + 255) / 256, 256, 0, stream>>>(Wi, DV + DE, CI, 0, Bpi);
  prepwpack_kernel<<<(CH * 832 + 255) / 256, 256, 0, stream>>>(Wh, DH, CH, 0, Bph);
  prepwpack_kernel<<<(CO * 832 + 255) / 256, 256, 0, stream>>>(Wo, 0, CO, 1, Bpo);

  // ---- V -> bf16 (into Vb16, aliases Hb; dead before fusedmp1 writes Hb) ----
  packv_kernel<<<(NN * (LDV / 8) + 255) / 256, 256, 0, stream>>>(V, Vb16);
  // ---- per-position tail (aliases Q; dead before gemmq1 writes Q) ----
  packet_kernel<<<(NE * 4 + 255) / 256, 256, 0, stream>>>(V, Ef, perm, psrc, Et);

  // ---- H0p (perm-ordered) ----
  h0_kernel<<<gGE, 256, 0, stream>>>(Vb16, Et, psrc, Bpi, bi, H0);

  // iter 1: Q = H0p@Wh; Hbp[rp] = relu(H0p[rp] + a_n - Qp[p])
  gemmq_kernel<<<gGE, 256, 0, stream>>>(H0, Bph, Q);
  fusedmp_kernel<<<gG, 256, 0, stream>>>(Q, H0, offsets, rpos, bh, 0, Hb);

  // iter 2: Q = Hbp@Wh; Hrev[p] = relu(H0p[rp] + a_n - Qp[p])  (seq write)
  gemmq_kernel<<<gGE, 256, 0, stream>>>(Hb, Bph, Q);
  fusedmp_kernel<<<gG, 256, 0, stream>>>(Q, H0, offsets, rpos, bh, 1, Hrev);

  // Q dead now: fill Abuf(=Q) V-columns + padding
  packav_kernel<<<(NNPAD * (KO / 8) + 255) / 256, 256, 0, stream>>>(V, Abuf);

  // readout: Mv[n] = sum_{p in seg(n)} Hrev[p]  (fully sequential)
  gatherseq_kernel<<<gG, 256, 0, stream>>>(Hrev, offsets, Abuf);
  out_kernel<<<gON, 256, 0, stream>>>(Abuf, Bpo, bo, (float*)d_out);
}